// Round 8
// baseline (197.564 us; speedup 1.0000x reference)
//
#include <hip/hip_runtime.h>

typedef unsigned short u16;
typedef unsigned int   u32;

typedef __attribute__((ext_vector_type(4))) short short4v;
typedef __attribute__((ext_vector_type(8))) short bf16x8;  // 8 bf16 (4 VGPRs)
typedef __attribute__((ext_vector_type(4))) float f32x4;

// Problem: B=8, C=256, N=4096, heads=8, d=32, P=64. Inputs fp32 (auto-detect),
// output FP32. r19: BK=32 dbuf (34.8KB LDS, 4 blocks/CU) — FAILED: raw
// s_barrier + vmcnt(0) fence left ds_reads (lgkmcnt) pending across the
// barrier -> WAR race with next iteration's global_load_lds overwrite.
// r20: per-iteration __syncthreads() (full vmcnt+lgkmcnt drain) closes the
// race; dbuf overlap preserved (stage issued before compute, drains at the
// iteration-end barrier). All else unchanged from r19.

__device__ __forceinline__ float bf2f(u16 u){
  union { u32 i; float f; } v; v.i = ((u32)u) << 16; return v.f;
}
__device__ __forceinline__ u16 f2bf(float f){
  u32 u = __float_as_uint(f);
  u32 r = u + 0x7FFFu + ((u >> 16) & 1u);   // RNE
  return (u16)(r >> 16);
}

__device__ __forceinline__ void gload_lds16(const u16* g, u16* l){
  __builtin_amdgcn_global_load_lds((const __attribute__((address_space(1))) void*)g,
                                   (__attribute__((address_space(3))) void*)l,
                                   16, 0, 0);
}

// ---------------------------------------------------------------------------
// K0a: dtype detector on x. flag=1 => fp32 input.
// ---------------------------------------------------------------------------
__global__ void k_detect(const u16* __restrict__ x, u32* __restrict__ flag){
  __shared__ int cnt[256];
  const int t = threadIdx.x;
  int c = 0;
  #pragma unroll
  for(int i = 0; i < 4; i++){
    u16 v = x[t * 4 + i];
    int e = (v >> 7) & 0xFF;
    if(e >= 112 && e <= 134) c++;
  }
  cnt[t] = c;
  __syncthreads();
  for(int s = 128; s > 0; s >>= 1){
    if(t < s) cnt[t] += cnt[t + s];
    __syncthreads();
  }
  if(t == 0) *flag = (cnt[0] < 800) ? 1u : 0u;
}

// ---------------------------------------------------------------------------
// K0 (merged): x transpose (y<4) + all small weight/EF/temp convs (y==4).
// Grid (64, 5, 8).
// ---------------------------------------------------------------------------
__global__ __launch_bounds__(256) void k_conv_all(const void* __restrict__ xsrc,
                                                  const void* __restrict__ Wsa,
                                                  const void* __restrict__ EF,
                                                  const void* __restrict__ Wsc,
                                                  const void* __restrict__ t2,
                                                  const void* __restrict__ tsc,
                                                  u16* __restrict__ xb,
                                                  u16* __restrict__ xT,
                                                  float* __restrict__ Wsaf,
                                                  u16* __restrict__ Wcat,
                                                  u16* __restrict__ EFT,
                                                  float* __restrict__ tf,
                                                  const u32* __restrict__ flag){
  __shared__ u16 T[64][72];
  const int t = threadIdx.x;
  const bool isf32 = (*flag != 0);
  if(blockIdx.y < 4){
    // ---- convT: x -> xb[b][c][n] + xT[b][n][c]
    const int n0 = blockIdx.x * 64, c0 = blockIdx.y * 64, b = blockIdx.z;
    const int cl = t >> 2, ns = (t & 3) * 16;
    const size_t srcoff = ((size_t)(b * 256 + c0 + cl)) * 4096 + n0 + ns;
    u16 e[16];
    if(isf32){
      const float* sp = (const float*)xsrc + srcoff;
      #pragma unroll
      for(int i = 0; i < 4; i++){
        const float4 v = *(const float4*)(sp + i * 4);
        e[i*4+0] = f2bf(v.x); e[i*4+1] = f2bf(v.y);
        e[i*4+2] = f2bf(v.z); e[i*4+3] = f2bf(v.w);
      }
    } else {
      const u16* sp = (const u16*)xsrc + srcoff;
      *(uint4*)&e[0] = *(const uint4*)sp;
      *(uint4*)&e[8] = *(const uint4*)(sp + 8);
    }
    u16* xbp = xb + srcoff;
    *(uint4*)xbp       = *(uint4*)&e[0];
    *(uint4*)(xbp + 8) = *(uint4*)&e[8];
    #pragma unroll
    for(int i = 0; i < 16; i++) T[ns + i][cl] = e[i];
    __syncthreads();
    const int nl = t >> 2, cs = (t & 3) * 16;
    u16* xtp = xT + ((size_t)b * 4096 + n0 + nl) * 256 + c0 + cs;
    *(uint4*)xtp       = *(const uint4*)&T[nl][cs];
    *(uint4*)(xtp + 8) = *(const uint4*)&T[nl][cs + 8];
    return;
  }
  // ---- misc convs, mid in [0, 417)
  const int mid = blockIdx.x + 64 * blockIdx.z;
  if(mid < 256){
    const int i0 = (mid * 256 + t) * 4;
    float4 o;
    if(isf32){
      o = *(const float4*)((const float*)Wsa + i0);
    } else {
      const uint2 a = *(const uint2*)((const u16*)Wsa + i0);
      o.x = bf2f((u16)(a.x & 0xFFFF)); o.y = bf2f((u16)(a.x >> 16));
      o.z = bf2f((u16)(a.y & 0xFFFF)); o.w = bf2f((u16)(a.y >> 16));
    }
    *(float4*)(Wsaf + i0) = o;
    if(i0 < 65536){
      uint2 pk;
      pk.x = (u32)f2bf(o.x) | ((u32)f2bf(o.y) << 16);
      pk.y = (u32)f2bf(o.z) | ((u32)f2bf(o.w) << 16);
      *(uint2*)(Wcat + i0) = pk;
    }
  } else if(mid < 320){
    const int n0 = (mid - 256) * 64;
    const int nl = t >> 2, p0 = (t & 3) * 16;
    const size_t off = (size_t)(n0 + nl) * 64 + p0;
    u16 e[16];
    if(isf32){
      const float* sp = (const float*)EF + off;
      #pragma unroll
      for(int i = 0; i < 4; i++){
        const float4 v = *(const float4*)(sp + i * 4);
        e[i*4+0] = f2bf(v.x); e[i*4+1] = f2bf(v.y);
        e[i*4+2] = f2bf(v.z); e[i*4+3] = f2bf(v.w);
      }
    } else {
      const u16* sp = (const u16*)EF + off;
      *(uint4*)&e[0] = *(const uint4*)sp;
      *(uint4*)&e[8] = *(const uint4*)(sp + 8);
    }
    #pragma unroll
    for(int i = 0; i < 16; i++) T[p0 + i][nl] = e[i];
    __syncthreads();
    const int pr = t >> 2, nn = (t & 3) * 16;
    u16* dp = EFT + (size_t)pr * 4096 + n0 + nn;
    *(uint4*)dp       = *(const uint4*)&T[pr][nn];
    *(uint4*)(dp + 8) = *(const uint4*)&T[pr][nn + 8];
  } else if(mid < 416){
    const int i0 = ((mid - 320) * 256 + t) * 8;
    u16* dst = Wcat + 65536;
    if(isf32){
      const float4 a = *(const float4*)((const float*)Wsc + i0);
      const float4 b = *(const float4*)((const float*)Wsc + i0 + 4);
      uint4 o;
      o.x = (u32)f2bf(a.x) | ((u32)f2bf(a.y) << 16);
      o.y = (u32)f2bf(a.z) | ((u32)f2bf(a.w) << 16);
      o.z = (u32)f2bf(b.x) | ((u32)f2bf(b.y) << 16);
      o.w = (u32)f2bf(b.z) | ((u32)f2bf(b.w) << 16);
      *(uint4*)(dst + i0) = o;
    } else {
      *(uint4*)(dst + i0) = *(const uint4*)((const u16*)Wsc + i0);
    }
  } else if(mid == 416){
    if(t < 16){
      const void* s = (t < 8) ? t2 : tsc;
      const int i = t & 7;
      if(isf32) tf[t] = ((const float*)s)[i];
      else      tf[t] = bf2f(((const u16*)s)[i]);
    }
  }
}

// ---------------------------------------------------------------------------
// K1 (merged): fused QKV GEMM (y<8) + split-K MFMA xef partials (y==8).
// Grid (32, 9, 8).
// QKV: 2-phase dbuf at BK=32 (LDS 34.8KB -> 4 blocks/CU). Each iter:
// {STAGE next (issue); COMPUTE cur; __syncthreads()} — syncthreads drains
// vmcnt AND lgkmcnt (race-free; r19's raw-barrier variant left ds_reads
// pending across the barrier -> WAR race).
// ---------------------------------------------------------------------------
__global__ __launch_bounds__(256) void k_qkv_xef(const u16* __restrict__ Wc,
                                                 const u16* __restrict__ xT,
                                                 const u16* __restrict__ xb,
                                                 const u16* __restrict__ EFT,
                                                 u16* __restrict__ Y,
                                                 float* __restrict__ nrmp,
                                                 float* __restrict__ xefp){
  __shared__ union {
    struct { u16 W0[128][32]; u16 X0[128][32];
             u16 W1[128][32]; u16 X1[128][32]; } d;
    u16 Cs[128][136];
  } L;
  const int t = threadIdx.x;
  const int w = t >> 6, lane = t & 63;
  const int fm = lane & 15, fq = lane >> 4;

  if(blockIdx.y == 8){
    // ---- xef partition: mh = x&1, s = x>>1, b = z
    const int mh = blockIdx.x & 1, s = blockIdx.x >> 1, b = blockIdx.z;
    const int c0 = mh * 128 + w * 32;
    const u16* ar = xb + ((size_t)(b * 256 + c0 + fm)) * 4096 + s * 256 + fq * 8;
    const u16* br = EFT + (size_t)fm * 4096 + s * 256 + fq * 8;
    f32x4 acc[2][4] = {};
    #pragma unroll
    for(int kk = 0; kk < 8; kk++){
      bf16x8 bfr[4];
      #pragma unroll
      for(int nt = 0; nt < 4; nt++)
        bfr[nt] = *(const bf16x8*)(br + (size_t)nt * 16 * 4096 + kk * 32);
      #pragma unroll
      for(int mt = 0; mt < 2; mt++){
        bf16x8 af = *(const bf16x8*)(ar + (size_t)mt * 16 * 4096 + kk * 32);
        #pragma unroll
        for(int nt = 0; nt < 4; nt++)
          acc[mt][nt] = __builtin_amdgcn_mfma_f32_16x16x32_bf16(af, bfr[nt],
                                                                acc[mt][nt], 0, 0, 0);
      }
    }
    float* dst = xefp + (size_t)s * 131072 + (size_t)(b * 256 + c0) * 64;
    #pragma unroll
    for(int mt = 0; mt < 2; mt++)
      #pragma unroll
      for(int nt = 0; nt < 4; nt++)
        #pragma unroll
        for(int r = 0; r < 4; r++)
          dst[(mt * 16 + fq * 4 + r) * 64 + nt * 16 + fm] = acc[mt][nt][r];
    return;
  }

  // ---- QKV partition
  const int n0 = blockIdx.x * 128, m0 = blockIdx.y * 128, b = blockIdx.z;
  const int wm = w >> 1, wn = w & 1;
  const int lr = lane >> 2;                  // 16 rows / gload (64B rows)
  const int lc = (lane & 3) * 8;             // 4 x 16B slots per row
  const u16* gw = Wc + (size_t)m0 * 256;
  const u16* gx = xT + ((size_t)b * 4096 + n0) * 256;
  f32x4 acc[4][4] = {};

#define QKV_STAGE(Wbuf, Xbuf, kc) do{                                          \
    _Pragma("unroll")                                                          \
    for(int i_ = 0; i_ < 2; i_++){                                             \
      const int row_ = w * 32 + i_ * 16;                                       \
      gload_lds16(gw + (size_t)(row_ + lr) * 256 + (kc) + lc, &Wbuf[row_][0]); \
      gload_lds16(gx + (size_t)(row_ + lr) * 256 + (kc) + lc, &Xbuf[row_][0]); \
    } }while(0)

#define QKV_COMPUTE(Wbuf, Xbuf) do{                                            \
    bf16x8 af_[4], bx_[4];                                                     \
    _Pragma("unroll")                                                          \
    for(int mt_ = 0; mt_ < 4; mt_++)                                           \
      af_[mt_] = *(const bf16x8*)&Wbuf[wm * 64 + mt_ * 16 + fm][fq * 8];       \
    _Pragma("unroll")                                                          \
    for(int nt_ = 0; nt_ < 4; nt_++)                                           \
      bx_[nt_] = *(const bf16x8*)&Xbuf[wn * 64 + nt_ * 16 + fm][fq * 8];       \
    _Pragma("unroll")                                                          \
    for(int mt_ = 0; mt_ < 4; mt_++)                                           \
      _Pragma("unroll")                                                        \
      for(int nt_ = 0; nt_ < 4; nt_++)                                         \
        acc[mt_][nt_] = __builtin_amdgcn_mfma_f32_16x16x32_bf16(               \
            af_[mt_], bx_[nt_], acc[mt_][nt_], 0, 0, 0);                       \
    }while(0)

  // prologue: stage tile 0, full drain
  QKV_STAGE(L.d.W0, L.d.X0, 0);
  __syncthreads();
  #pragma unroll
  for(int it = 0; it < 8; it++){
    if(it & 1){
      if(it < 7) QKV_STAGE(L.d.W0, L.d.X0, (it + 1) * 32);
      QKV_COMPUTE(L.d.W1, L.d.X1);
    } else {
      if(it < 7) QKV_STAGE(L.d.W1, L.d.X1, (it + 1) * 32);
      QKV_COMPUTE(L.d.W0, L.d.X0);
    }
    __syncthreads();   // drains vmcnt (stage) AND lgkmcnt (ds_reads) — race-free
  }

  #pragma unroll
  for(int mt = 0; mt < 4; mt++)
    #pragma unroll
    for(int nt = 0; nt < 4; nt++)
      #pragma unroll
      for(int r = 0; r < 4; r++)
        L.Cs[wm * 64 + mt * 16 + fq * 4 + r][wn * 64 + nt * 16 + fm] =
          f2bf(acc[mt][nt][r]);
  __syncthreads();
  const bool do_norm = (blockIdx.y < 6);       // rows 0:768 = q|qc|kc
  float* npb = nrmp + (size_t)blockIdx.x * 6144 + (size_t)b * 768 + m0;
  #pragma unroll
  for(int i = 0; i < 8; i++){
    const int row = i * 16 + (t >> 4), ce = (t & 15) * 8;
    uint4 pk = *(const uint4*)&L.Cs[row][ce];
    *(uint4*)(Y + ((size_t)b * 1024 + m0 + row) * 4096 + n0 + ce) = pk;
    if(do_norm){
      u16 e[8]; *(uint4*)e = pk;
      float s = 0.f;
      #pragma unroll
      for(int k2 = 0; k2 < 8; k2++){ float v = bf2f(e[k2]); s += v * v; }
      #pragma unroll
      for(int m2 = 1; m2 < 16; m2 <<= 1) s += __shfl_xor(s, m2, 16);
      if((t & 15) == 0) npb[row] = s;
    }
  }
#undef QKV_STAGE
#undef QKV_COMPUTE
}

// ---------------------------------------------------------------------------
// K2b: xef reduce (blocks 0:128) + norm finalize (blocks 128:152).
// ---------------------------------------------------------------------------
__global__ __launch_bounds__(256) void k_xred_nfin(const float* __restrict__ xefp,
                                                   float* __restrict__ xef,
                                                   const float* __restrict__ nrmp,
                                                   float* __restrict__ inv3){
  const int bx = blockIdx.x, t = threadIdx.x;
  if(bx < 128){
    const int i0 = (bx * 256 + t) * 4;
    float4 a = *(const float4*)(xefp + i0);
    #pragma unroll
    for(int s = 1; s < 16; s++){
      const float4 v = *(const float4*)(xefp + (size_t)s * 131072 + i0);
      a.x += v.x; a.y += v.y; a.z += v.z; a.w += v.w;
    }
    *(float4*)(xef + i0) = a;
  } else {
    const int tid = (bx - 128) * 256 + t;          // [0, 6144)
    float s = 0.f;
    #pragma unroll
    for(int nt = 0; nt < 32; nt++) s += nrmp[(size_t)nt * 6144 + tid];
    const int b = tid / 768, m = tid - b * 768;
    inv3[(m >> 8) * 2048 + b * 256 + (m & 255)] = 1.0f / fmaxf(sqrtf(s), 1e-12f);
  }
}

// ---------------------------------------------------------------------------
// K3 (merged): gram (x<64) + kv4b (x>=64). Grid (192, 8).
// ---------------------------------------------------------------------------
__device__ __forceinline__ bf16x8 ld_frag8(const u16* p){
  short4v lo = *(const short4v*)p;
  short4v hi = *(const short4v*)(p + 4);
  bf16x8 r;
  r[0]=lo[0]; r[1]=lo[1]; r[2]=lo[2]; r[3]=lo[3];
  r[4]=hi[0]; r[5]=hi[1]; r[6]=hi[2]; r[7]=hi[3];
  return r;
}

__global__ __launch_bounds__(256) void k_kv_gram(const u16* __restrict__ Y,
                                                 const float* __restrict__ Wsaf,
                                                 const float* __restrict__ xef,
                                                 const float* __restrict__ invsa,
                                                 u16* __restrict__ kpT,
                                                 u16* __restrict__ vpb,
                                                 float* __restrict__ Gp){
  const int t = threadIdx.x;
  if(blockIdx.x < 64){
    // ---- gram: s = x>>3, h = x&7, b = y
    const int s = blockIdx.x >> 3, h = blockIdx.x & 7, b = blockIdx.y;
    const int w = t >> 6, lane = t & 63;
    const int fm = lane & 15, fq = lane >> 4;
    const int j0 = (w >> 1) * 16, e0 = (w & 1) * 16;
    const u16* qrow = Y + (size_t)(b * 1024 + 256 + h * 32 + j0 + fm) * 4096;
    const u16* krow = Y + (size_t)(b * 1024 + 512 + h * 32 + e0 + fm) * 4096;
    f32x4 acc = {};
    const int nb0 = s * 512 + fq * 8;
    #pragma unroll 4
    for(int it = 0; it < 16; it++){
      const int nb = nb0 + it * 32;
      bf16x8 a  = ld_frag8(qrow + nb);
      bf16x8 bb = ld_frag8(krow + nb);
      acc = __builtin_amdgcn_mfma_f32_16x16x32_bf16(a, bb, acc, 0, 0, 0);
    }
    float* dst = Gp + ((size_t)((s * 8 + b) * 8 + h) * 1024);
    #pragma unroll
    for(int r = 0; r < 4; r++)
      dst[(j0 + fq * 4 + r) * 32 + e0 + fm] = acc[r];
    return;
  }
  // ---- kv4b: rblk = x-64, b = y
  const int ri = t >> 6, p = t & 63;
  const int r = (blockIdx.x - 64) * 4 + ri, b = blockIdx.y;
  const int row_w = (r < 256) ? (256 + r) : (512 + r);
  const float* wr = Wsaf + (size_t)row_w * 256;
  const float* xr = xef + (size_t)(b * 256) * 64 + p;
  float acc = 0.f;
  for(int c = 0; c < 256; c++)
    acc += wr[c] * xr[(size_t)c * 64];
  if(r < 256){
    const float sc = invsa[b * 256 + r];
    kpT[((size_t)(b * 8 + (r >> 5)) * 64 + p) * 32 + (r & 31)] = f2bf(acc * sc);
  } else {
    const int rv = r - 256;
    vpb[((size_t)(b * 8 + (rv >> 5)) * 32 + (rv & 31)) * 64 + p] = f2bf(acc);
  }
}

// ---------------------------------------------------------------------------
// K4 (merged): spatial attention (x<64) + channel softmax (x==64, y==0).
// Grid (65, 8, 8).
// ---------------------------------------------------------------------------
__global__ __launch_bounds__(256) void k_sa_sm(const u16* __restrict__ Y,
                                               const u16* __restrict__ kpT,
                                               const u16* __restrict__ vpb,
                                               const float* __restrict__ tf,
                                               const float* __restrict__ Gp,
                                               const float* __restrict__ invq,
                                               const float* __restrict__ invk,
                                               u16* __restrict__ xsa,
                                               float* __restrict__ attn){
  __shared__ u16 As[64][36];
  __shared__ u16 Ks[64][36];
  __shared__ u16 Vs[32][68];
  __shared__ u16 Ps[64][68];
  __shared__ u16 Cs[32][68];
  const int t = threadIdx.x;
  if(blockIdx.x == 64){
    if(blockIdx.y != 0) return;
    // ---- channel softmax, b = z
    const int b = blockIdx.z;
    const int h = t >> 5, j = t & 31;
    const float tm = tf[8 + h];
    const float iq = invq[b * 256 + h * 32 + j];
    float v[32];
    float m = -1e30f;
    #pragma unroll
    for(int e = 0; e < 32; e++){
      float g = 0.f;
      #pragma unroll
      for(int s = 0; s < 8; s++)
        g += Gp[(size_t)s * 65536 + (size_t)(b * 8 + h) * 1024 + j * 32 + e];
      float val = g * iq * invk[b * 256 + h * 32 + e] * tm;
      v[e] = val; m = fmaxf(m, val);
    }
    float sum = 0.f;
    #pragma unroll
    for(int e = 0; e < 32; e++){ v[e] = __expf(v[e] - m); sum += v[e]; }
    const float inv = 1.0f / sum;
    #pragma unroll
    for(int e = 0; e < 32; e++)
      attn[(size_t)(b * 8 + h) * 1024 + j * 32 + e] = v[e] * inv;
    return;
  }
  // ---- spatial attention
  const int ntile = blockIdx.x, h = blockIdx.y, b = blockIdx.z;
  const int n0 = ntile * 64;
  const int w = t >> 6, lane = t & 63;
  const int fm = lane & 15, fq = lane >> 4;
  {
    const int j = t >> 3, ns = (t & 7) * 8;
    const u16* src = Y + (size_t)(b * 1024 + h * 32 + j) * 4096 + n0 + ns;
    uint4 v = *(const uint4*)src;
    u16 e[8]; *(uint4*)e = v;
    #pragma unroll
    for(int i = 0; i < 8; i++) As[ns + i][j] = e[i];
  }
  {
    const int p = t >> 2, jb = (t & 3) * 8;
    *(uint4*)&Ks[p][jb] =
      *(const uint4*)(kpT + ((size_t)(b * 8 + h) * 64 + p) * 32 + jb);
  }
  {
    const int jv = t >> 3, ps = (t & 7) * 8;
    *(uint4*)&Vs[jv][ps] =
      *(const uint4*)(vpb + ((size_t)(b * 8 + h) * 32 + jv) * 64 + ps);
  }
  __syncthreads();
  bf16x8 a = ld_frag8(&As[w * 16 + fm][fq * 8]);
  f32x4 lg[4];
  #pragma unroll
  for(int pt = 0; pt < 4; pt++){
    bf16x8 bk = ld_frag8(&Ks[pt * 16 + fm][fq * 8]);
    f32x4 z = {};
    lg[pt] = __builtin_amdgcn_mfma_f32_16x16x32_bf16(a, bk, z, 0, 0, 0);
  }
  const float tm = tf[h];
  float sinv[4];
  #pragma unroll
  for(int r = 0; r < 4; r++){
    float v0 = lg[0][r]*tm, v1 = lg[1][r]*tm, v2 = lg[2][r]*tm, v3 = lg[3][r]*tm;
    float mx = fmaxf(fmaxf(v0, v1), fmaxf(v2, v3));
    #pragma unroll
    for(int m = 1; m < 16; m <<= 1) mx = fmaxf(mx, __shfl_xor(mx, m, 16));
    v0 = __expf(v0 - mx); v1 = __expf(v1 - mx);
    v2 = __expf(v2 - mx); v3 = __expf(v3 - mx);
    float s = v0 + v1 + v2 + v3;
    #pragma unroll
    for(int m = 1; m < 16; m <<= 1) s += __shfl_xor(s, m, 16);
    sinv[r] = 1.0f / s;
    const int nrow = w * 16 + fq * 4 + r;
    Ps[nrow][fm]      = f2bf(v0);
    Ps[nrow][16 + fm] = f2bf(v1);
    Ps[nrow][32 + fm] = f2bf(v2);
    Ps[nrow][48 + fm] = f2bf(v3);
  }
  f32x4 o[2] = {};
  #pragma unroll
  for(int ks = 0; ks < 2; ks++){
    bf16x8 ap = ld_frag8(&Ps[w * 16 + fm][ks * 32 + fq * 8]);
    #pragma unroll
    for(int jt = 0; jt < 2; jt++){
      bf16x8 bv = ld_frag8(&Vs[jt * 16 + fm][ks * 32 + fq * 8]);
      o[jt] = __builtin_amdgcn_mfma_f32_16x16x32_bf16(ap, bv, o[jt], 0, 0, 0);
    }
  }
  #pragma unroll
  for(int jt = 0; jt < 2; jt++)
    #pragma unroll
    for(int r = 0; r < 4; r++)
      Cs[jt * 16 + fm][w * 16 + fq * 4 + r] = f2bf(o[jt][r] * sinv[r]);
  __syncthreads();
  {
    const int jv = t >> 3, ns = (t & 7) * 8;
    u16 e[8];
    #pragma unroll
    for(int i = 0; i < 8; i++) e[i] = Cs[jv][ns + i];
    *(uint4*)(xsa + ((size_t)(b * 8 + h) * 32 + jv) * 4096 + n0 + ns) = *(uint4*)e;
  }
}

// ---------------------------------------------------------------------------
// K7: MFMA out-writer (unchanged).
// ---------------------------------------------------------------------------
__global__ __launch_bounds__(256) void k_out_mfma(const u16* __restrict__ Y,
                                                  const float* __restrict__ attn,
                                                  const u16* __restrict__ xsa,
                                                  float* __restrict__ out){
  __shared__ u16 Vt[32][516];
  __shared__ u16 xs[32][16][34];
  __shared__ u16 Ah[32][40];
  __shared__ u16 Al[32][40];
  const int t = threadIdx.x;
  const int jg = blockIdx.x, hc = blockIdx.y, b = blockIdx.z;
  const int nn0 = jg * 512;
  const int w = t >> 6, lane = t & 63;
  const int fm = lane & 15, fq = lane >> 4;
  {
    const float4 v = *(const float4*)(attn + (size_t)(b * 8 + hc) * 1024 + t * 4);
    const int j = t >> 3, e0 = (t & 7) * 4;
    float vv[4] = {v.x, v.y, v.z, v.w};
    #pragma unroll
    for(int i = 0; i < 4; i++){
      u16 hi = f2bf(vv[i]);
      Ah[j][e0 + i] = hi;
      Al[j][e0 + i] = f2bf(vv[i] - bf2f(hi));
    }
  }
  {
    const int e = t >> 3, ch = (t & 7) * 64;
    const u16* src = Y + (size_t)(b * 1024 + 768 + hc * 32 + e) * 4096 + nn0 + ch;
    #pragma unroll
    for(int i = 0; i < 8; i++){
      uint4 v = *(const uint4*)(src + i * 8);
      uint2 lo; lo.x = v.x; lo.y = v.y;
      uint2 hi; hi.x = v.z; hi.y = v.w;
      *(uint2*)&Vt[e][ch + i * 8]     = lo;
      *(uint2*)&Vt[e][ch + i * 8 + 4] = hi;
    }
  }
  #pragma unroll
  for(int rep = 0; rep < 2; rep++){
    const int s = rep * 256 + t;
    const int hj = s >> 4, nh = s & 15;
    const int h = hj & 7, jj = hj >> 3;
    const u16* src = xsa + ((size_t)(b * 8 + h) * 32 + jg * 4 + jj) * 4096 + nh * 256 + hc * 32;
    uint4 v0 = *(const uint4*)src;
    uint4 v1 = *(const uint4*)(src + 8);
    u32* d32 = (u32*)&xs[hj][nh][0];
    d32[0] = v0.x; d32[1] = v0.y; d32[2] = v0.z; d32[3] = v0.w;
    d32[4] = v1.x; d32[5] = v1.y; d32[6] = v1.z; d32[7] = v1.w;
    uint4 v2 = *(const uint4*)(src + 16);
    uint4 v3 = *(const uint4*)(src + 24);
    d32[8]  = v2.x; d32[9]  = v2.y; d32[10] = v2.z; d32[11] = v2.w;
    d32[12] = v3.x; d32[13] = v3.y; d32[14] = v3.z; d32[15] = v3.w;
  }
  __syncthreads();
  bf16x8 ah[2], al[2];
  #pragma unroll
  for(int mt = 0; mt < 2; mt++){
    ah[mt] = *(const bf16x8*)&Ah[mt * 16 + fm][fq * 8];
    al[mt] = *(const bf16x8*)&Al[mt * 16 + fm][fq * 8];
  }
  f32x4 acc[2][8] = {};
  #pragma unroll
  for(int nt = 0; nt < 8; nt++){
    const int colb = w * 128 + nt * 16 + fm;
    bf16x8 bv;
    #pragma unroll
    for(int i = 0; i < 8; i++) bv[i] = (short)Vt[fq * 8 + i][colb];
    #pragma unroll
    for(int mt = 0; mt < 2; mt++){
      acc[mt][nt] = __builtin_amdgcn_mfma_f32_16x16x32_bf16(ah[mt], bv, acc[mt][nt], 0, 0, 0);
      acc[mt][nt] = __builtin_amdgcn_mfma_f32_16x16x32_bf16(al[mt], bv, acc[mt][nt], 0, 0, 0);
    }
  }
  #pragma unroll
  for(int mt = 0; mt < 2; mt++)
    #pragma unroll
    for(int nt = 0; nt < 8; nt++){
      const int col = w * 128 + nt * 16 + fm;
      float* op = out + (size_t)(b * 256 + hc * 32 + mt * 16 + fq * 4) * 4096 + nn0 + col;
      #pragma unroll
      for(int r = 0; r < 4; r++){
        const float sa = bf2f(xs[w * 8 + nt][fm][mt * 16 + fq * 4 + r]);
        op[(size_t)r * 4096] = acc[mt][nt][r] + sa;
      }
    }
}

// ---------------------------------------------------------------------------
// Workspace layout (bytes).
// ---------------------------------------------------------------------------
#define OFF_XB    ((size_t)0)            // u16 [8][256][4096]  16,777,216 (reused as xsa)
#define OFF_XT    ((size_t)16777216)     // u16 [8][4096][256]  16,777,216
#define OFF_Y     ((size_t)33554432)     // u16 [8][1024][4096] 67,108,864
#define OFF_WSAF  ((size_t)100663296)    // f32 [1024][256]      1,048,576
#define OFF_WCAT  ((size_t)101711872)    // u16 [1024][256]        524,288
#define OFF_EFT   ((size_t)102236160)    // u16 [64][4096]         524,288
#define OFF_XEF   ((size_t)103284736)    // f32 [8][256][64]       524,288
#define OFF_KPT   ((size_t)103809024)    // u16 [8][8][64][32]     262,144
#define OFF_VPB   ((size_t)104071168)    // u16 [8][8][32][64]     262,144
#define OFF_ISA   ((size_t)104333312)    // f32 [3][8][256]         24,576 (isa|iqc|ikc)
#define OFF_IQC   ((size_t)104341504)
#define OFF_IKC   ((size_t)104349696)
#define OFF_GP    ((size_t)104357888)    // f32 [8][8][8][32][32] 2,097,152
#define OFF_ATT   ((size_t)106455040)    // f32 [8][8][32][32]      262,144
#define OFF_TF    ((size_t)106717184)    // f32 [16]
#define OFF_FLAG  ((size_t)106717248)    // u32
#define OFF_NRM   ((size_t)106717312)    // f32 [32][8][768]        786,432
#define OFF_XEFP  ((size_t)107503744)    // f32 [16][8][256][64]  8,388,608

extern "C" void kernel_launch(void* const* d_in, const int* in_sizes, int n_in,
                              void* d_out, int out_size, void* d_ws, size_t ws_size,
                              hipStream_t stream){
  (void)in_sizes; (void)n_in; (void)out_size; (void)ws_size;
  char* ws = (char*)d_ws;
  u16*   xb    = (u16*)  (ws + OFF_XB);
  u16*   xsa   = (u16*)  (ws + OFF_XB);    // overlay
  u16*   xT    = (u16*)  (ws + OFF_XT);
  u16*   Y     = (u16*)  (ws + OFF_Y);
  float* Wsaf  = (float*)(ws + OFF_WSAF);
  u16*   Wcat  = (u16*)  (ws + OFF_WCAT);
  u16*   EFT   = (u16*)  (ws + OFF_EFT);
  float* xef   = (float*)(ws + OFF_XEF);
  u16*   kpT   = (u16*)  (ws + OFF_KPT);
  u16*   vpb   = (u16*)  (ws + OFF_VPB);
  float* invsa = (float*)(ws + OFF_ISA);
  float* invqc = (float*)(ws + OFF_IQC);
  float* invkc = (float*)(ws + OFF_IKC);
  float* Gp    = (float*)(ws + OFF_GP);
  float* attn  = (float*)(ws + OFF_ATT);
  float* tf    = (float*)(ws + OFF_TF);
  u32*   flag  = (u32*)  (ws + OFF_FLAG);
  float* nrmp  = (float*)(ws + OFF_NRM);
  float* xefp  = (float*)(ws + OFF_XEFP);
  float* out = (float*)d_out;

  // 1) dtype detect  2) all canonicalization in one launch
  k_detect<<<1, 256, 0, stream>>>((const u16*)d_in[0], flag);
  k_conv_all<<<dim3(64, 5, 8), 256, 0, stream>>>(d_in[0], d_in[1], d_in[2],
                                                 d_in[4], d_in[3], d_in[5],
                                                 xb, xT, Wsaf, Wcat, EFT, tf, flag);
  // 3) fused QKV GEMM (2-phase dbuf, BK=32, race-free syncthreads) + xef
  k_qkv_xef<<<dim3(32, 9, 8), 256, 0, stream>>>(Wcat, xT, xb, EFT, Y, nrmp, xefp);
  // 4) xef reduce + norm finalize
  k_xred_nfin<<<152, 256, 0, stream>>>(xefp, xef, nrmp, invsa);
  // 5) kpT/vpb + channel gram (co-resident)
  k_kv_gram<<<dim3(192, 8), 256, 0, stream>>>(Y, Wsaf, xef, invsa, kpT, vpb, Gp);
  // 6) spatial attention + channel softmax (co-resident)
  k_sa_sm<<<dim3(65, 8, 8), 256, 0, stream>>>(Y, kpT, vpb, tf, Gp, invsa + 2048,
                                              invsa + 4096, xsa, attn);
  // 7) MFMA out-writer
  k_out_mfma<<<dim3(8, 8, 8), 256, 0, stream>>>(Y, attn, xsa, out);
}